// Round 13
// baseline (318.955 us; speedup 1.0000x reference)
//
#include <hip/hip_runtime.h>
#include <hip/hip_bf16.h>
#include <string.h>

#define B_ 16
#define CIN_ 512
#define COUT_ 512
#define SDIM_ 512
#define HIN_ 32
#define WIN_ 32
#define HOUT_ 64
#define WOUT_ 64

#define LIN_SCALE_C 0.044194173824159216f
#define CONV_SCALE_C 0.014731391274719742f

typedef short short8 __attribute__((ext_vector_type(8)));
typedef float f32x4 __attribute__((ext_vector_type(4)));
typedef float f32x16 __attribute__((ext_vector_type(16)));

typedef const __attribute__((address_space(1))) void* gptr_t;
typedef __attribute__((address_space(3))) void* sptr_t;

// ALWAYS offset=0 (offset-param semantics unverified on gfx950); compile-time
// address constants are folded into inst_offset by the compiler safely.
#define GLDS0(SRC, DST) \
    __builtin_amdgcn_global_load_lds((gptr_t)(SRC), (sptr_t)(DST), 16, 0, 0)

// ---------------- style: one wave per (b,i); shuffle-reduce 512-dot
__global__ void style_kernel(const float* __restrict__ w, const float* __restrict__ lin_w,
                             const float* __restrict__ lin_b, float* __restrict__ s) {
    const int gw   = (blockIdx.x * 256 + threadIdx.x) >> 6;   // 0..8191
    const int lane = threadIdx.x & 63;
    const int b = gw >> 9, i = gw & 511;
    const float* wr = w + b * SDIM_;
    const float* lw = lin_w + i * SDIM_;
    float acc = 0.f;
    #pragma unroll
    for (int j = 0; j < 8; ++j) acc += wr[lane + j * 64] * lw[lane + j * 64];
    #pragma unroll
    for (int off = 32; off; off >>= 1) acc += __shfl_xor(acc, off);
    if (lane == 0) s[b * CIN_ + i] = acc * LIN_SCALE_C + lin_b[i];
}

// ---------------- weights: coalesced LDS-staged transpose.
__global__ void prep_weights(const float* __restrict__ conv_w, __hip_bfloat16* __restrict__ w2,
                             float* __restrict__ wsq, float* __restrict__ zbuf) {
    __shared__ float xs[4608];
    const int o = blockIdx.x;
    const int tid = threadIdx.x;
    for (int idx = tid; idx < 4608; idx += 256) xs[idx] = conv_w[o * 4608 + idx];
    __syncthreads();
    for (int i = tid; i < CIN_; i += 256) {   // stride 9 coprime to 32 banks
        float ss = 0.f;
        #pragma unroll
        for (int kk = 0; kk < 9; ++kk) {
            float v = xs[i * 9 + kk] * CONV_SCALE_C;
            ss += v * v;
            w2[o * 4608 + kk * 512 + i] = __float2bfloat16(v);
        }
        wsq[o * CIN_ + i] = ss;
    }
    if (blockIdx.x == 0 && tid < 256) zbuf[tid] = 0.f;  // 1024 B zero page
}

// ---------------- demod: one wave per (b,o); shuffle-reduce
__global__ void demod_kernel(const float* __restrict__ wsq, const float* __restrict__ s,
                             float* __restrict__ demod) {
    const int gw   = (blockIdx.x * 256 + threadIdx.x) >> 6;
    const int lane = threadIdx.x & 63;
    const int b = gw >> 9, o = gw & 511;
    const float* sr = s + b * CIN_;
    const float* wr = wsq + o * CIN_;
    float acc = 0.f;
    #pragma unroll
    for (int j = 0; j < 8; ++j) {
        float sv = sr[lane + j * 64];
        acc += wr[lane + j * 64] * sv * sv;
    }
    #pragma unroll
    for (int off = 32; off; off >>= 1) acc += __shfl_xor(acc, off);
    if (lane == 0) demod[b * COUT_ + o] = 1.0f / sqrtf(acc + 1e-8f);
}

// ---------------- bilinear 2x upsample + modulate, NCHW fp32 -> NHWC bf16 (short8 stores)
__global__ void upsample_mod_kernel(const float* __restrict__ x, const float* __restrict__ s,
                                    __hip_bfloat16* __restrict__ xq) {
    __shared__ float xs[10 * 32 * 33];
    __shared__ float ssh[32];
    const int ht = blockIdx.x;
    const int ct = blockIdx.y;
    const int b  = blockIdx.z;
    const int tid = threadIdx.x;
    const int ho0 = ht * 16, h0 = ht * 8, c0 = ct * 32;

    if (tid < 32) ssh[tid] = s[b * CIN_ + c0 + tid];
    for (int idx = tid; idx < 10240; idx += 256) {
        int ch = idx / 320; int rem = idx - ch * 320;
        int rr = rem >> 5;  int col = rem & 31;
        int srow = h0 - 1 + rr; srow = min(max(srow, 0), 31);
        xs[(rr * 32 + col) * 33 + ch] = x[((b * CIN_ + c0 + ch) * HIN_ + srow) * WIN_ + col];
    }
    __syncthreads();

    for (int e = tid; e < 4096; e += 256) {
        int c8 = e & 3; int wo = (e >> 2) & 63; int hr = e >> 8;
        int ri0 = (hr + (hr & 1)) >> 1;
        float wlo_h = (hr & 1) ? 0.75f : 0.25f;
        int clo = (wo - 2 + (wo & 1)) >> 1;
        float wlo_w = (wo & 1) ? 0.75f : 0.25f;
        int chi = min(clo + 1, 31); clo = max(clo, 0);
        const float* r0p = xs + (ri0 * 32) * 33;
        const float* r1p = xs + ((ri0 + 1) * 32) * 33;
        short8 v;
        #pragma unroll
        for (int q = 0; q < 8; ++q) {
            const int c = c8 * 8 + q;
            float v0 = r0p[clo * 33 + c];
            float v1 = r0p[chi * 33 + c];
            float v2 = r1p[clo * 33 + c];
            float v3 = r1p[chi * 33 + c];
            float rlo = wlo_w * v0 + (1.f - wlo_w) * v1;
            float rhi = wlo_w * v2 + (1.f - wlo_w) * v3;
            float val = (wlo_h * rlo + (1.f - wlo_h) * rhi) * ssh[c];
            __hip_bfloat16 hv = __float2bfloat16(val);
            unsigned short us;
            __builtin_memcpy(&us, &hv, 2);
            v[q] = (short)us;
        }
        *(short8*)(xq + (((size_t)(b * 64) + ho0 + hr) * 64 + wo) * 512 + c0 + c8 * 8) = v;
    }
}

// ---------------- implicit-GEMM conv, 256x256 tile, BK=32, 4-deep LDS ring.
// r11-verified sync (per-window counted vmcnt(4) + barrier), literal-offset windows,
// same staging + chunk-XOR swizzle. MFMA switched to 32x32x16 (16/window/wave instead
// of 32 of 16x16x32): matrix-pipe cost 1233 -> ~1033 cyc/window/CU (m119 rates), and
// half the MFMA issue slots frees issue bandwidth for ds_reads. Per-wave tile still
// 128x64 = 4Mx2N 32x32 tiles, acc 8 x f32x16. Reads per window unchanged (12 b128;
// each 16-lane phase = 16 consecutive rows at one swizzled chunk = r11's verified
// 0-conflict per-phase pattern).
__global__ __launch_bounds__(512)
void conv_kernel(const __hip_bfloat16* __restrict__ xq,
                 const __hip_bfloat16* __restrict__ w2,
                 const float* __restrict__ demod,
                 const float* __restrict__ noise,
                 const float* __restrict__ nw_p,
                 float* __restrict__ out,
                 const __hip_bfloat16* __restrict__ zbuf) {
    extern __shared__ __hip_bfloat16 smem[];
    __hip_bfloat16* As = smem;           // 4 slots x [256][32] elems (64 KB)
    __hip_bfloat16* Bs = smem + 32768;   // 4 slots x [256][32]       (64 KB)

    const int bid = blockIdx.x;
    const int swz = (bid & 7) * 64 + (bid >> 3);
    const int b  = swz >> 5;
    const int mt = (swz >> 4) & 1;
    const int nt = swz & 15;
    const int o0 = mt * 256;
    const int p0 = nt * 256;

    const int tid  = threadIdx.x;
    const int lane = tid & 63;
    const int wave = tid >> 6;
    const int wm = wave >> 2, wn = wave & 3;

    // staging coords (r3/r11): 4 threads/row (64B); source chunk swizzle-permuted
    const int srow = tid >> 2;                               // 0..127
    const int schk = (((tid & 3) ^ ((tid >> 3) & 3))) * 8;
    const int aoff = (o0 + srow) * 4608 + schk;
    const int brow_lo = nt * 4 + (srow >> 6);
    const int bcol = srow & 63;
    const int sdst = tid * 8;

    // frag read offsets for 32x32 operands: lane l -> row l&31, k-chunk l>>5 (half h
    // adds 2 chunks). phys chunk = logical ^ ((row>>1)&3) (row base mult of 32).
    const int lrow32 = lane & 31;
    const int g      = lane >> 5;
    const int xr     = (lrow32 >> 1) & 3;
    const int ck0    = ((0 + g) ^ xr) * 8;    // h=0 chunk offset (elems)
    const int ck1    = ((2 + g) ^ xr) * 8;    // h=1
    const __hip_bfloat16* Ar0 = As + (wm * 128 + lrow32) * 32 + ck0;
    const __hip_bfloat16* Ar1 = As + (wm * 128 + lrow32) * 32 + ck1;
    const __hip_bfloat16* Br0 = Bs + (wn * 64 + lrow32) * 32 + ck0;
    const __hip_bfloat16* Br1 = Bs + (wn * 64 + lrow32) * 32 + ck1;

    // hoisted staging bases
    __hip_bfloat16* Ad = As + sdst;
    __hip_bfloat16* Bd = Bs + sdst;
    const __hip_bfloat16* aB0 = w2 + aoff;   // +512 elems per kk; h=1 at +589824
    const __hip_bfloat16* aB1 = aB0 + 589824;

    f32x16 acc[4][2] = {};

    #define MKB(DH, DW, H) \
        ((((unsigned)(brow_lo + (H) * 2 + (DH)) < 64u) && ((unsigned)(bcol + (DW)) < 64u)) \
            ? xq + (size_t)((b * 64 + brow_lo + (H) * 2 + (DH)) * 64 + (bcol + (DW))) * 512 + schk \
            : zbuf)

    const __hip_bfloat16* pB0c = MKB(-1, -1, 0);
    const __hip_bfloat16* pB1c = MKB(-1, -1, 1);

    // prologue: stage tiles u=0 (slot 0) and u=1 (slot 1), kk=0
    GLDS0(aB0,       Ad);        GLDS0(aB1,       Ad + 4096);
    GLDS0(pB0c,      Bd);        GLDS0(pB1c,      Bd + 4096);
    GLDS0(aB0 + 32,  Ad + 8192); GLDS0(aB1 + 32,  Ad + 8192 + 4096);
    GLDS0(pB0c + 32, Bd + 8192); GLDS0(pB1c + 32, Bd + 8192 + 4096);
    asm volatile("s_waitcnt vmcnt(4)" ::: "memory");
    __builtin_amdgcn_s_barrier();

    #define MFMA32(A, Bv, C) __builtin_amdgcn_mfma_f32_32x32x16_bf16(A, Bv, C, 0, 0, 0)

    // window V (literal 0..15): reads slot V&3 (tile t=kk*16+V); stages tile u=t+2
    // into slot (V+2)&3; r11 sync verbatim.
    #define WIN(V) do { \
        short8 a00 = *(const short8*)(Ar0 + ((V) & 3) * 8192 + 0 * 1024); \
        short8 a10 = *(const short8*)(Ar0 + ((V) & 3) * 8192 + 1 * 1024); \
        short8 a20 = *(const short8*)(Ar0 + ((V) & 3) * 8192 + 2 * 1024); \
        short8 a30 = *(const short8*)(Ar0 + ((V) & 3) * 8192 + 3 * 1024); \
        short8 a01 = *(const short8*)(Ar1 + ((V) & 3) * 8192 + 0 * 1024); \
        short8 a11 = *(const short8*)(Ar1 + ((V) & 3) * 8192 + 1 * 1024); \
        short8 a21 = *(const short8*)(Ar1 + ((V) & 3) * 8192 + 2 * 1024); \
        short8 a31 = *(const short8*)(Ar1 + ((V) & 3) * 8192 + 3 * 1024); \
        short8 b00 = *(const short8*)(Br0 + ((V) & 3) * 8192 + 0 * 1024); \
        short8 b10 = *(const short8*)(Br0 + ((V) & 3) * 8192 + 1 * 1024); \
        short8 b01 = *(const short8*)(Br1 + ((V) & 3) * 8192 + 0 * 1024); \
        short8 b11 = *(const short8*)(Br1 + ((V) & 3) * 8192 + 1 * 1024); \
        if ((V) < 14) { \
            GLDS0(aB0 + ((V) + 2) * 32,          Ad + (((V) + 2) & 3) * 8192); \
            GLDS0(aB1 + ((V) + 2) * 32,          Ad + (((V) + 2) & 3) * 8192 + 4096); \
            GLDS0(pB0c + (((V) + 2) & 15) * 32,  Bd + (((V) + 2) & 3) * 8192); \
            GLDS0(pB1c + (((V) + 2) & 15) * 32,  Bd + (((V) + 2) & 3) * 8192 + 4096); \
            asm volatile("s_waitcnt vmcnt(4)" ::: "memory"); \
        } else if (kk < 8) { \
            GLDS0(aB0 + ((V) + 2) * 32,          Ad + (((V) + 2) & 3) * 8192); \
            GLDS0(aB1 + ((V) + 2) * 32,          Ad + (((V) + 2) & 3) * 8192 + 4096); \
            GLDS0(pB0n + (((V) + 2) & 15) * 32,  Bd + (((V) + 2) & 3) * 8192); \
            GLDS0(pB1n + (((V) + 2) & 15) * 32,  Bd + (((V) + 2) & 3) * 8192 + 4096); \
            asm volatile("s_waitcnt vmcnt(4)" ::: "memory"); \
        } else { \
            asm volatile("s_waitcnt vmcnt(0)" ::: "memory"); \
        } \
        __builtin_amdgcn_s_barrier(); \
        __builtin_amdgcn_s_setprio(1); \
        acc[0][0] = MFMA32(a00, b00, acc[0][0]); \
        acc[0][1] = MFMA32(a00, b10, acc[0][1]); \
        acc[1][0] = MFMA32(a10, b00, acc[1][0]); \
        acc[1][1] = MFMA32(a10, b10, acc[1][1]); \
        acc[2][0] = MFMA32(a20, b00, acc[2][0]); \
        acc[2][1] = MFMA32(a20, b10, acc[2][1]); \
        acc[3][0] = MFMA32(a30, b00, acc[3][0]); \
        acc[3][1] = MFMA32(a30, b10, acc[3][1]); \
        acc[0][0] = MFMA32(a01, b01, acc[0][0]); \
        acc[0][1] = MFMA32(a01, b11, acc[0][1]); \
        acc[1][0] = MFMA32(a11, b01, acc[1][0]); \
        acc[1][1] = MFMA32(a11, b11, acc[1][1]); \
        acc[2][0] = MFMA32(a21, b01, acc[2][0]); \
        acc[2][1] = MFMA32(a21, b11, acc[2][1]); \
        acc[3][0] = MFMA32(a31, b01, acc[3][0]); \
        acc[3][1] = MFMA32(a31, b11, acc[3][1]); \
        __builtin_amdgcn_s_setprio(0); \
    } while (0)

    #pragma unroll 1
    for (int kk = 0; kk < 9; ++kk) {
        const int kn  = kk + 1;
        const int kdn = (kn * 11) >> 5;          // kn/3
        const int dhn = kdn - 1, dwn = kn - kdn * 3 - 1;
        const __hip_bfloat16* pB0n = MKB(dhn, dwn, 0);
        const __hip_bfloat16* pB1n = MKB(dhn, dwn, 1);

        WIN(0);  WIN(1);  WIN(2);  WIN(3);
        WIN(4);  WIN(5);  WIN(6);  WIN(7);
        WIN(8);  WIN(9);  WIN(10); WIN(11);
        WIN(12); WIN(13); WIN(14); WIN(15);

        pB0c = pB0n; pB1c = pB1n;
        aB0 += 512;  aB1 += 512;
    }
    #undef WIN
    #undef MFMA32
    #undef MKB

    // epilogue: 32x32 C/D layout (m74/m101): col = lane&31, row = (j&3)+8*(j>>2)+4*(lane>>5)
    const float nwv = nw_p[0];
    const int col32 = lane & 31;
    const int hi4 = (lane >> 5) * 4;
    float nz2[2];
    nz2[0] = noise[b * 4096 + p0 + wn * 64 + col32] * nwv;
    nz2[1] = noise[b * 4096 + p0 + wn * 64 + 32 + col32] * nwv;
    #pragma unroll
    for (int mi = 0; mi < 4; ++mi) {
        const int obase = o0 + wm * 128 + mi * 32 + hi4;
        #pragma unroll
        for (int jq = 0; jq < 4; ++jq) {
            float dm[4];
            #pragma unroll
            for (int jj = 0; jj < 4; ++jj) dm[jj] = demod[b * COUT_ + obase + jq * 8 + jj];
            #pragma unroll
            for (int jj = 0; jj < 4; ++jj) {
                const int j = jq * 4 + jj;
                const int cout = obase + jq * 8 + jj;
                #pragma unroll
                for (int ni = 0; ni < 2; ++ni) {
                    float v = acc[mi][ni][j] * dm[jj] + nz2[ni];
                    v = (v >= 0.f ? v : 0.2f * v) * 1.4142135623730951f;
                    out[(b * COUT_ + cout) * 4096 + p0 + wn * 64 + ni * 32 + col32] = v;
                }
            }
        }
    }
}

extern "C" void kernel_launch(void* const* d_in, const int* in_sizes, int n_in,
                              void* d_out, int out_size, void* d_ws, size_t ws_size,
                              hipStream_t stream) {
    const float* x      = (const float*)d_in[0];
    const float* w      = (const float*)d_in[1];
    const float* noise  = (const float*)d_in[2];
    const float* lin_w  = (const float*)d_in[3];
    const float* lin_b  = (const float*)d_in[4];
    const float* conv_w = (const float*)d_in[5];
    const float* nw     = (const float*)d_in[6];
    float* out = (float*)d_out;

    char* ws = (char*)d_ws;
    __hip_bfloat16* xq = (__hip_bfloat16*)ws;                    // 67108864 B (NHWC bf16)
    __hip_bfloat16* w2 = (__hip_bfloat16*)(ws + 67108864);       //  4718592 B
    float* s     = (float*)(ws + 71827456);                      //    32768 B
    float* demod = (float*)(ws + 71860224);                      //    32768 B
    float* wsq   = (float*)(ws + 71892992);                      //  1048576 B
    float* zbuf  = (float*)(ws + 72941568);                      //     1024 B (zero page)

    static int lds_set = 0;
    if (!lds_set) {
        (void)hipFuncSetAttribute((const void*)conv_kernel,
                                  hipFuncAttributeMaxDynamicSharedMemorySize, 131072);
        lds_set = 1;
    }

    style_kernel<<<2048, 256, 0, stream>>>(w, lin_w, lin_b, s);
    prep_weights<<<512, 256, 0, stream>>>(conv_w, w2, wsq, zbuf);
    demod_kernel<<<2048, 256, 0, stream>>>(wsq, s, demod);
    upsample_mod_kernel<<<dim3(4, 16, 16), 256, 0, stream>>>(x, s, xq);
    conv_kernel<<<512, 512, 131072, stream>>>(xq, w2, demod, noise, nw, out,
                                              (const __hip_bfloat16*)zbuf);
}

// Round 14
// 283.890 us; speedup vs baseline: 1.1235x; 1.1235x over previous
//
#include <hip/hip_runtime.h>
#include <hip/hip_bf16.h>
#include <string.h>

#define B_ 16
#define CIN_ 512
#define COUT_ 512
#define SDIM_ 512
#define HIN_ 32
#define WIN_ 32
#define HOUT_ 64
#define WOUT_ 64

#define LIN_SCALE_C 0.044194173824159216f
#define CONV_SCALE_C 0.014731391274719742f

typedef short short8 __attribute__((ext_vector_type(8)));
typedef float f32x4 __attribute__((ext_vector_type(4)));

typedef const __attribute__((address_space(1))) void* gptr_t;
typedef __attribute__((address_space(3))) void* sptr_t;

// ALWAYS offset=0 (offset-param semantics unverified on gfx950); compile-time
// address constants are folded into inst_offset by the compiler safely.
#define GLDS0(SRC, DST) \
    __builtin_amdgcn_global_load_lds((gptr_t)(SRC), (sptr_t)(DST), 16, 0, 0)

// ---------------- fused A: style (blocks 0..2047) + prep_weights (blocks 2048..2559)
__global__ void style_prep_kernel(const float* __restrict__ w, const float* __restrict__ lin_w,
                                  const float* __restrict__ lin_b, float* __restrict__ s,
                                  const float* __restrict__ conv_w, __hip_bfloat16* __restrict__ w2,
                                  float* __restrict__ wsq, float* __restrict__ zbuf) {
    __shared__ float xs[4608];
    const int bx = blockIdx.x;
    const int tid = threadIdx.x;
    if (bx < 2048) {
        // ---- style: one wave per (b,i); shuffle-reduce 512-dot
        const int gw   = (bx * 256 + tid) >> 6;   // 0..8191
        const int lane = tid & 63;
        const int b = gw >> 9, i = gw & 511;
        const float* wr = w + b * SDIM_;
        const float* lw = lin_w + i * SDIM_;
        float acc = 0.f;
        #pragma unroll
        for (int j = 0; j < 8; ++j) acc += wr[lane + j * 64] * lw[lane + j * 64];
        #pragma unroll
        for (int off = 32; off; off >>= 1) acc += __shfl_xor(acc, off);
        if (lane == 0) s[b * CIN_ + i] = acc * LIN_SCALE_C + lin_b[i];
    } else {
        // ---- prep_weights: coalesced LDS-staged transpose
        const int o = bx - 2048;
        for (int idx = tid; idx < 4608; idx += 256) xs[idx] = conv_w[o * 4608 + idx];
        __syncthreads();
        for (int i = tid; i < CIN_; i += 256) {   // stride 9 coprime to 32 banks
            float ss = 0.f;
            #pragma unroll
            for (int kk = 0; kk < 9; ++kk) {
                float v = xs[i * 9 + kk] * CONV_SCALE_C;
                ss += v * v;
                w2[o * 4608 + kk * 512 + i] = __float2bfloat16(v);
            }
            wsq[o * CIN_ + i] = ss;
        }
        if (o == 0 && tid < 256) zbuf[tid] = 0.f;  // 1024 B zero page
    }
}

// ---------------- fused B: demod (blocks 0..2047) + upsample (blocks 2048..3071)
__global__ void demod_upsample_kernel(const float* __restrict__ wsq, const float* __restrict__ s,
                                      float* __restrict__ demod,
                                      const float* __restrict__ x, __hip_bfloat16* __restrict__ xq) {
    __shared__ float xs[10 * 32 * 33];
    __shared__ float ssh[32];
    const int bx = blockIdx.x;
    const int tid = threadIdx.x;
    if (bx < 2048) {
        // ---- demod: one wave per (b,o); shuffle-reduce
        const int gw   = (bx * 256 + tid) >> 6;
        const int lane = tid & 63;
        const int b = gw >> 9, o = gw & 511;
        const float* sr = s + b * CIN_;
        const float* wr = wsq + o * CIN_;
        float acc = 0.f;
        #pragma unroll
        for (int j = 0; j < 8; ++j) {
            float sv = sr[lane + j * 64];
            acc += wr[lane + j * 64] * sv * sv;
        }
        #pragma unroll
        for (int off = 32; off; off >>= 1) acc += __shfl_xor(acc, off);
        if (lane == 0) demod[b * COUT_ + o] = 1.0f / sqrtf(acc + 1e-8f);
    } else {
        // ---- bilinear 2x upsample + modulate, NCHW fp32 -> NHWC bf16 (short8 stores)
        const int u  = bx - 2048;           // 0..1023
        const int ht = u & 3;
        const int ct = (u >> 2) & 15;
        const int b  = u >> 6;
        const int ho0 = ht * 16, h0 = ht * 8, c0 = ct * 32;

        if (tid < 32) ssh[tid] = s[b * CIN_ + c0 + tid];
        for (int idx = tid; idx < 10240; idx += 256) {
            int ch = idx / 320; int rem = idx - ch * 320;
            int rr = rem >> 5;  int col = rem & 31;
            int srow = h0 - 1 + rr; srow = min(max(srow, 0), 31);
            xs[(rr * 32 + col) * 33 + ch] = x[((b * CIN_ + c0 + ch) * HIN_ + srow) * WIN_ + col];
        }
        __syncthreads();

        for (int e = tid; e < 4096; e += 256) {
            int c8 = e & 3; int wo = (e >> 2) & 63; int hr = e >> 8;
            int ri0 = (hr + (hr & 1)) >> 1;
            float wlo_h = (hr & 1) ? 0.75f : 0.25f;
            int clo = (wo - 2 + (wo & 1)) >> 1;
            float wlo_w = (wo & 1) ? 0.75f : 0.25f;
            int chi = min(clo + 1, 31); clo = max(clo, 0);
            const float* r0p = xs + (ri0 * 32) * 33;
            const float* r1p = xs + ((ri0 + 1) * 32) * 33;
            short8 v;
            #pragma unroll
            for (int q = 0; q < 8; ++q) {
                const int c = c8 * 8 + q;
                float v0 = r0p[clo * 33 + c];
                float v1 = r0p[chi * 33 + c];
                float v2 = r1p[clo * 33 + c];
                float v3 = r1p[chi * 33 + c];
                float rlo = wlo_w * v0 + (1.f - wlo_w) * v1;
                float rhi = wlo_w * v2 + (1.f - wlo_w) * v3;
                float val = (wlo_h * rlo + (1.f - wlo_h) * rhi) * ssh[c];
                __hip_bfloat16 hv = __float2bfloat16(val);
                unsigned short us;
                __builtin_memcpy(&us, &hv, 2);
                v[q] = (short)us;
            }
            *(short8*)(xq + (((size_t)(b * 64) + ho0 + hr) * 64 + wo) * 512 + c0 + c8 * 8) = v;
        }
    }
}

// ---------------- implicit-GEMM conv, 256x256 tile, BK=32, 4-deep LDS ring, counted vmcnt.
// r11-VERIFIED KERNEL, VERBATIM (conv 249 us, MfmaUtil 59.4%, bank-conflict 0):
// kk-outer x 16 literal windows; all staging and ds_read addresses are base +
// compile-time constants; B pointers + validity hoisted to once per kk.
__global__ __launch_bounds__(512)
void conv_kernel(const __hip_bfloat16* __restrict__ xq,
                 const __hip_bfloat16* __restrict__ w2,
                 const float* __restrict__ demod,
                 const float* __restrict__ noise,
                 const float* __restrict__ nw_p,
                 float* __restrict__ out,
                 const __hip_bfloat16* __restrict__ zbuf) {
    extern __shared__ __hip_bfloat16 smem[];
    __hip_bfloat16* As = smem;           // 4 slots x [256][32] elems (64 KB)
    __hip_bfloat16* Bs = smem + 32768;   // 4 slots x [256][32]       (64 KB)

    const int bid = blockIdx.x;
    const int swz = (bid & 7) * 64 + (bid >> 3);
    const int b  = swz >> 5;
    const int mt = (swz >> 4) & 1;
    const int nt = swz & 15;
    const int o0 = mt * 256;
    const int p0 = nt * 256;

    const int tid  = threadIdx.x;
    const int lane = tid & 63;
    const int wave = tid >> 6;
    const int wm = wave >> 2, wn = wave & 3;

    // staging coords (r3): 4 threads/row (64B); source chunk swizzle-permuted
    const int srow = tid >> 2;                               // 0..127
    const int schk = (((tid & 3) ^ ((tid >> 3) & 3))) * 8;
    const int aoff = (o0 + srow) * 4608 + schk;
    const int brow_lo = nt * 4 + (srow >> 6);
    const int bcol = srow & 63;
    const int sdst = tid * 8;

    // frag read offsets (r3 swizzle)
    const int lrow = lane & 15;
    const int pko = ((lane >> 4) ^ ((lrow >> 1) & 3)) * 8;
    const int ard = (wm * 128 + lrow) * 32 + pko;
    const int brd = (wn * 64 + lrow) * 32 + pko;

    // hoisted bases
    const __hip_bfloat16* Ar = As + ard;     // ds_read base; window offsets are literals
    const __hip_bfloat16* Br = Bs + brd;
    __hip_bfloat16* Ad = As + sdst;          // glds dest base; slot/half offsets literal
    __hip_bfloat16* Bd = Bs + sdst;
    const __hip_bfloat16* aB0 = w2 + aoff;   // advances 512 elems per kk; h=1 at +589824
    const __hip_bfloat16* aB1 = aB0 + 589824;

    f32x4 acc[8][4] = {};

    // B staging pointer for (dh,dw,h): validity folded to zbuf fallback (per-kk, not per-window)
    #define MKB(DH, DW, H) \
        ((((unsigned)(brow_lo + (H) * 2 + (DH)) < 64u) && ((unsigned)(bcol + (DW)) < 64u)) \
            ? xq + (size_t)((b * 64 + brow_lo + (H) * 2 + (DH)) * 64 + (bcol + (DW))) * 512 + schk \
            : zbuf)

    const __hip_bfloat16* pB0c = MKB(-1, -1, 0);
    const __hip_bfloat16* pB1c = MKB(-1, -1, 1);

    // prologue: stage tiles u=0 (slot 0) and u=1 (slot 1), kk=0 (offsets in ELEMENTS)
    GLDS0(aB0,       Ad);        GLDS0(aB1,       Ad + 4096);
    GLDS0(pB0c,      Bd);        GLDS0(pB1c,      Bd + 4096);
    GLDS0(aB0 + 32,  Ad + 8192); GLDS0(aB1 + 32,  Ad + 8192 + 4096);
    GLDS0(pB0c + 32, Bd + 8192); GLDS0(pB1c + 32, Bd + 8192 + 4096);
    asm volatile("s_waitcnt vmcnt(4)" ::: "memory");
    __builtin_amdgcn_s_barrier();

    #define MR(AV, MI) \
        acc[MI][0] = __builtin_amdgcn_mfma_f32_16x16x32_bf16(AV, b0_, acc[MI][0], 0, 0, 0); \
        acc[MI][1] = __builtin_amdgcn_mfma_f32_16x16x32_bf16(AV, b1_, acc[MI][1], 0, 0, 0); \
        acc[MI][2] = __builtin_amdgcn_mfma_f32_16x16x32_bf16(AV, b2_, acc[MI][2], 0, 0, 0); \
        acc[MI][3] = __builtin_amdgcn_mfma_f32_16x16x32_bf16(AV, b3_, acc[MI][3], 0, 0, 0)

    // window V (literal 0..15): reads slot V&3 (tile t=kk*16+V); stages tile u=t+2
    // into slot (V+2)&3. A source offset u*32 elems = kk*512 (in aB0) + (V+2)*32 (literal).
    // B channel offset (u&15)*32 elems (literal).
    #define WIN(V) do { \
        short8 a0_ = *(const short8*)(Ar + (V & 3) * 8192 + 0 * 512); \
        short8 a1_ = *(const short8*)(Ar + (V & 3) * 8192 + 1 * 512); \
        short8 a2_ = *(const short8*)(Ar + (V & 3) * 8192 + 2 * 512); \
        short8 a3_ = *(const short8*)(Ar + (V & 3) * 8192 + 3 * 512); \
        short8 a4_ = *(const short8*)(Ar + (V & 3) * 8192 + 4 * 512); \
        short8 a5_ = *(const short8*)(Ar + (V & 3) * 8192 + 5 * 512); \
        short8 a6_ = *(const short8*)(Ar + (V & 3) * 8192 + 6 * 512); \
        short8 a7_ = *(const short8*)(Ar + (V & 3) * 8192 + 7 * 512); \
        short8 b0_ = *(const short8*)(Br + (V & 3) * 8192 + 0 * 512); \
        short8 b1_ = *(const short8*)(Br + (V & 3) * 8192 + 1 * 512); \
        short8 b2_ = *(const short8*)(Br + (V & 3) * 8192 + 2 * 512); \
        short8 b3_ = *(const short8*)(Br + (V & 3) * 8192 + 3 * 512); \
        if ((V) < 14) { \
            GLDS0(aB0 + ((V) + 2) * 32,          Ad + (((V) + 2) & 3) * 8192); \
            GLDS0(aB1 + ((V) + 2) * 32,          Ad + (((V) + 2) & 3) * 8192 + 4096); \
            GLDS0(pB0c + (((V) + 2) & 15) * 32,  Bd + (((V) + 2) & 3) * 8192); \
            GLDS0(pB1c + (((V) + 2) & 15) * 32,  Bd + (((V) + 2) & 3) * 8192 + 4096); \
            asm volatile("s_waitcnt vmcnt(4)" ::: "memory"); \
        } else if (kk < 8) { \
            GLDS0(aB0 + ((V) + 2) * 32,          Ad + (((V) + 2) & 3) * 8192); \
            GLDS0(aB1 + ((V) + 2) * 32,          Ad + (((V) + 2) & 3) * 8192 + 4096); \
            GLDS0(pB0n + (((V) + 2) & 15) * 32,  Bd + (((V) + 2) & 3) * 8192); \
            GLDS0(pB1n + (((V) + 2) & 15) * 32,  Bd + (((V) + 2) & 3) * 8192 + 4096); \
            asm volatile("s_waitcnt vmcnt(4)" ::: "memory"); \
        } else { \
            asm volatile("s_waitcnt vmcnt(0)" ::: "memory"); \
        } \
        __builtin_amdgcn_s_barrier(); \
        __builtin_amdgcn_s_setprio(1); \
        MR(a0_, 0); MR(a1_, 1); MR(a2_, 2); MR(a3_, 3); \
        MR(a4_, 4); MR(a5_, 5); MR(a6_, 6); MR(a7_, 7); \
        __builtin_amdgcn_s_setprio(0); \
    } while (0)

    #pragma unroll 1
    for (int kk = 0; kk < 9; ++kk) {
        const int kn  = kk + 1;
        const int kdn = (kn * 11) >> 5;          // kn/3
        const int dhn = kdn - 1, dwn = kn - kdn * 3 - 1;
        const __hip_bfloat16* pB0n = MKB(dhn, dwn, 0);
        const __hip_bfloat16* pB1n = MKB(dhn, dwn, 1);

        WIN(0);  WIN(1);  WIN(2);  WIN(3);
        WIN(4);  WIN(5);  WIN(6);  WIN(7);
        WIN(8);  WIN(9);  WIN(10); WIN(11);
        WIN(12); WIN(13); WIN(14); WIN(15);

        pB0c = pB0n; pB1c = pB1n;
        aB0 += 512;  aB1 += 512;
    }
    #undef WIN
    #undef MR
    #undef MKB

    // epilogue: demod * acc + nw*noise, leaky-relu * sqrt(2)
    const float nwv = nw_p[0];
    const int colp = lane & 15;
    const int rgrp = (lane >> 4) * 4;
    float nz[4];
    #pragma unroll
    for (int ni = 0; ni < 4; ++ni)
        nz[ni] = noise[b * 4096 + p0 + wn * 64 + ni * 16 + colp] * nwv;
    #pragma unroll
    for (int mi = 0; mi < 8; ++mi) {
        const int obase = o0 + wm * 128 + mi * 16 + rgrp;
        float dm[4];
        #pragma unroll
        for (int j = 0; j < 4; ++j) dm[j] = demod[b * COUT_ + obase + j];
        #pragma unroll
        for (int ni = 0; ni < 4; ++ni) {
            const int pix = p0 + wn * 64 + ni * 16 + colp;
            #pragma unroll
            for (int j = 0; j < 4; ++j) {
                float v = acc[mi][ni][j] * dm[j] + nz[ni];
                v = (v >= 0.f ? v : 0.2f * v) * 1.4142135623730951f;
                out[(b * COUT_ + obase + j) * 4096 + pix] = v;
            }
        }
    }
}

extern "C" void kernel_launch(void* const* d_in, const int* in_sizes, int n_in,
                              void* d_out, int out_size, void* d_ws, size_t ws_size,
                              hipStream_t stream) {
    const float* x      = (const float*)d_in[0];
    const float* w      = (const float*)d_in[1];
    const float* noise  = (const float*)d_in[2];
    const float* lin_w  = (const float*)d_in[3];
    const float* lin_b  = (const float*)d_in[4];
    const float* conv_w = (const float*)d_in[5];
    const float* nw     = (const float*)d_in[6];
    float* out = (float*)d_out;

    char* ws = (char*)d_ws;
    __hip_bfloat16* xq = (__hip_bfloat16*)ws;                    // 67108864 B (NHWC bf16)
    __hip_bfloat16* w2 = (__hip_bfloat16*)(ws + 67108864);       //  4718592 B
    float* s     = (float*)(ws + 71827456);                      //    32768 B
    float* demod = (float*)(ws + 71860224);                      //    32768 B
    float* wsq   = (float*)(ws + 71892992);                      //  1048576 B
    float* zbuf  = (float*)(ws + 72941568);                      //     1024 B (zero page)

    static int lds_set = 0;
    if (!lds_set) {
        (void)hipFuncSetAttribute((const void*)conv_kernel,
                                  hipFuncAttributeMaxDynamicSharedMemorySize, 131072);
        lds_set = 1;
    }

    style_prep_kernel<<<2560, 256, 0, stream>>>(w, lin_w, lin_b, s, conv_w, w2, wsq, zbuf);
    demod_upsample_kernel<<<3072, 256, 0, stream>>>(wsq, s, demod, x, xq);
    conv_kernel<<<512, 512, 131072, stream>>>(xq, w2, demod, noise, nw, out,
                                              (const __hip_bfloat16*)zbuf);
}

// Round 15
// 273.301 us; speedup vs baseline: 1.1670x; 1.0387x over previous
//
#include <hip/hip_runtime.h>
#include <hip/hip_bf16.h>
#include <string.h>

#define B_ 16
#define CIN_ 512
#define COUT_ 512
#define SDIM_ 512
#define HIN_ 32
#define WIN_ 32
#define HOUT_ 64
#define WOUT_ 64

#define LIN_SCALE_C 0.044194173824159216f
#define CONV_SCALE_C 0.014731391274719742f

typedef short short8 __attribute__((ext_vector_type(8)));
typedef float f32x4 __attribute__((ext_vector_type(4)));

typedef const __attribute__((address_space(1))) void* gptr_t;
typedef __attribute__((address_space(3))) void* sptr_t;

// ALWAYS offset=0 (offset-param semantics unverified on gfx950); compile-time
// address constants are folded into inst_offset by the compiler safely.
#define GLDS0(SRC, DST) \
    __builtin_amdgcn_global_load_lds((gptr_t)(SRC), (sptr_t)(DST), 16, 0, 0)

// ---------------- style: one wave per (b,i); shuffle-reduce 512-dot
__global__ void style_kernel(const float* __restrict__ w, const float* __restrict__ lin_w,
                             const float* __restrict__ lin_b, float* __restrict__ s) {
    const int gw   = (blockIdx.x * 256 + threadIdx.x) >> 6;   // 0..8191
    const int lane = threadIdx.x & 63;
    const int b = gw >> 9, i = gw & 511;
    const float* wr = w + b * SDIM_;
    const float* lw = lin_w + i * SDIM_;
    float acc = 0.f;
    #pragma unroll
    for (int j = 0; j < 8; ++j) acc += wr[lane + j * 64] * lw[lane + j * 64];
    #pragma unroll
    for (int off = 32; off; off >>= 1) acc += __shfl_xor(acc, off);
    if (lane == 0) s[b * CIN_ + i] = acc * LIN_SCALE_C + lin_b[i];
}

// ---------------- weights: coalesced LDS-staged transpose.
__global__ void prep_weights(const float* __restrict__ conv_w, __hip_bfloat16* __restrict__ w2,
                             float* __restrict__ wsq, float* __restrict__ zbuf) {
    __shared__ float xs[4608];
    const int o = blockIdx.x;
    const int tid = threadIdx.x;
    for (int idx = tid; idx < 4608; idx += 256) xs[idx] = conv_w[o * 4608 + idx];
    __syncthreads();
    for (int i = tid; i < CIN_; i += 256) {   // stride 9 coprime to 32 banks
        float ss = 0.f;
        #pragma unroll
        for (int kk = 0; kk < 9; ++kk) {
            float v = xs[i * 9 + kk] * CONV_SCALE_C;
            ss += v * v;
            w2[o * 4608 + kk * 512 + i] = __float2bfloat16(v);
        }
        wsq[o * CIN_ + i] = ss;
    }
    if (blockIdx.x == 0 && tid < 256) zbuf[tid] = 0.f;  // 1024 B zero page
}

// ---------------- demod: one wave per (b,o); shuffle-reduce
__global__ void demod_kernel(const float* __restrict__ wsq, const float* __restrict__ s,
                             float* __restrict__ demod) {
    const int gw   = (blockIdx.x * 256 + threadIdx.x) >> 6;
    const int lane = threadIdx.x & 63;
    const int b = gw >> 9, o = gw & 511;
    const float* sr = s + b * CIN_;
    const float* wr = wsq + o * CIN_;
    float acc = 0.f;
    #pragma unroll
    for (int j = 0; j < 8; ++j) {
        float sv = sr[lane + j * 64];
        acc += wr[lane + j * 64] * sv * sv;
    }
    #pragma unroll
    for (int off = 32; off; off >>= 1) acc += __shfl_xor(acc, off);
    if (lane == 0) demod[b * COUT_ + o] = 1.0f / sqrtf(acc + 1e-8f);
}

// ---------------- bilinear 2x upsample + modulate, NCHW fp32 -> NHWC bf16 (short8 stores)
__global__ void upsample_mod_kernel(const float* __restrict__ x, const float* __restrict__ s,
                                    __hip_bfloat16* __restrict__ xq) {
    __shared__ float xs[10 * 32 * 33];
    __shared__ float ssh[32];
    const int ht = blockIdx.x;
    const int ct = blockIdx.y;
    const int b  = blockIdx.z;
    const int tid = threadIdx.x;
    const int ho0 = ht * 16, h0 = ht * 8, c0 = ct * 32;

    if (tid < 32) ssh[tid] = s[b * CIN_ + c0 + tid];
    for (int idx = tid; idx < 10240; idx += 256) {
        int ch = idx / 320; int rem = idx - ch * 320;
        int rr = rem >> 5;  int col = rem & 31;
        int srow = h0 - 1 + rr; srow = min(max(srow, 0), 31);
        xs[(rr * 32 + col) * 33 + ch] = x[((b * CIN_ + c0 + ch) * HIN_ + srow) * WIN_ + col];
    }
    __syncthreads();

    for (int e = tid; e < 4096; e += 256) {
        int c8 = e & 3; int wo = (e >> 2) & 63; int hr = e >> 8;
        int ri0 = (hr + (hr & 1)) >> 1;
        float wlo_h = (hr & 1) ? 0.75f : 0.25f;
        int clo = (wo - 2 + (wo & 1)) >> 1;
        float wlo_w = (wo & 1) ? 0.75f : 0.25f;
        int chi = min(clo + 1, 31); clo = max(clo, 0);
        const float* r0p = xs + (ri0 * 32) * 33;
        const float* r1p = xs + ((ri0 + 1) * 32) * 33;
        short8 v;
        #pragma unroll
        for (int q = 0; q < 8; ++q) {
            const int c = c8 * 8 + q;
            float v0 = r0p[clo * 33 + c];
            float v1 = r0p[chi * 33 + c];
            float v2 = r1p[clo * 33 + c];
            float v3 = r1p[chi * 33 + c];
            float rlo = wlo_w * v0 + (1.f - wlo_w) * v1;
            float rhi = wlo_w * v2 + (1.f - wlo_w) * v3;
            float val = (wlo_h * rlo + (1.f - wlo_h) * rhi) * ssh[c];
            __hip_bfloat16 hv = __float2bfloat16(val);
            unsigned short us;
            __builtin_memcpy(&us, &hv, 2);
            v[q] = (short)us;
        }
        *(short8*)(xq + (((size_t)(b * 64) + ho0 + hr) * 64 + wo) * 512 + c0 + c8 * 8) = v;
    }
}

// ---------------- implicit-GEMM conv, 256x256 tile, BK=32, 4-deep LDS ring, counted vmcnt.
// r11-VERIFIED KERNEL (conv 249 us, MfmaUtil 59.4%, bank-conflict 0): kk-outer x 16
// literal windows; all staging and ds_read addresses are base + compile-time constants;
// B pointers + validity hoisted to once per kk.
__global__ __launch_bounds__(512)
void conv_kernel(const __hip_bfloat16* __restrict__ xq,
                 const __hip_bfloat16* __restrict__ w2,
                 const float* __restrict__ demod,
                 const float* __restrict__ noise,
                 const float* __restrict__ nw_p,
                 float* __restrict__ out,
                 const __hip_bfloat16* __restrict__ zbuf) {
    extern __shared__ __hip_bfloat16 smem[];
    __hip_bfloat16* As = smem;           // 4 slots x [256][32] elems (64 KB)
    __hip_bfloat16* Bs = smem + 32768;   // 4 slots x [256][32]       (64 KB)

    const int bid = blockIdx.x;
    const int swz = (bid & 7) * 64 + (bid >> 3);
    const int b  = swz >> 5;
    const int mt = (swz >> 4) & 1;
    const int nt = swz & 15;
    const int o0 = mt * 256;
    const int p0 = nt * 256;

    const int tid  = threadIdx.x;
    const int lane = tid & 63;
    const int wave = tid >> 6;
    const int wm = wave >> 2, wn = wave & 3;

    // staging coords (r3): 4 threads/row (64B); source chunk swizzle-permuted
    const int srow = tid >> 2;                               // 0..127
    const int schk = (((tid & 3) ^ ((tid >> 3) & 3))) * 8;
    const int aoff = (o0 + srow) * 4608 + schk;
    const int brow_lo = nt * 4 + (srow >> 6);
    const int bcol = srow & 63;
    const int sdst = tid * 8;

    // frag read offsets (r3 swizzle)
    const int lrow = lane & 15;
    const int pko = ((lane >> 4) ^ ((lrow >> 1) & 3)) * 8;
    const int ard = (wm * 128 + lrow) * 32 + pko;
    const int brd = (wn * 64 + lrow) * 32 + pko;

    // hoisted bases
    const __hip_bfloat16* Ar = As + ard;     // ds_read base; window offsets are literals
    const __hip_bfloat16* Br = Bs + brd;
    __hip_bfloat16* Ad = As + sdst;          // glds dest base; slot/half offsets literal
    __hip_bfloat16* Bd = Bs + sdst;
    const __hip_bfloat16* aB0 = w2 + aoff;   // advances 512 elems per kk; h=1 at +589824
    const __hip_bfloat16* aB1 = aB0 + 589824;

    f32x4 acc[8][4] = {};

    // B staging pointer for (dh,dw,h): validity folded to zbuf fallback (per-kk, not per-window)
    #define MKB(DH, DW, H) \
        ((((unsigned)(brow_lo + (H) * 2 + (DH)) < 64u) && ((unsigned)(bcol + (DW)) < 64u)) \
            ? xq + (size_t)((b * 64 + brow_lo + (H) * 2 + (DH)) * 64 + (bcol + (DW))) * 512 + schk \
            : zbuf)

    const __hip_bfloat16* pB0c = MKB(-1, -1, 0);
    const __hip_bfloat16* pB1c = MKB(-1, -1, 1);

    // prologue: stage tiles u=0 (slot 0) and u=1 (slot 1), kk=0 (offsets in ELEMENTS)
    GLDS0(aB0,       Ad);        GLDS0(aB1,       Ad + 4096);
    GLDS0(pB0c,      Bd);        GLDS0(pB1c,      Bd + 4096);
    GLDS0(aB0 + 32,  Ad + 8192); GLDS0(aB1 + 32,  Ad + 8192 + 4096);
    GLDS0(pB0c + 32, Bd + 8192); GLDS0(pB1c + 32, Bd + 8192 + 4096);
    asm volatile("s_waitcnt vmcnt(4)" ::: "memory");
    __builtin_amdgcn_s_barrier();

    #define MR(AV, MI) \
        acc[MI][0] = __builtin_amdgcn_mfma_f32_16x16x32_bf16(AV, b0_, acc[MI][0], 0, 0, 0); \
        acc[MI][1] = __builtin_amdgcn_mfma_f32_16x16x32_bf16(AV, b1_, acc[MI][1], 0, 0, 0); \
        acc[MI][2] = __builtin_amdgcn_mfma_f32_16x16x32_bf16(AV, b2_, acc[MI][2], 0, 0, 0); \
        acc[MI][3] = __builtin_amdgcn_mfma_f32_16x16x32_bf16(AV, b3_, acc[MI][3], 0, 0, 0)

    // window V (literal 0..15): reads slot V&3 (tile t=kk*16+V); stages tile u=t+2
    // into slot (V+2)&3. A source offset u*32 elems = kk*512 (in aB0) + (V+2)*32 (literal).
    // B channel offset (u&15)*32 elems (literal).
    #define WIN(V) do { \
        short8 a0_ = *(const short8*)(Ar + (V & 3) * 8192 + 0 * 512); \
        short8 a1_ = *(const short8*)(Ar + (V & 3) * 8192 + 1 * 512); \
        short8 a2_ = *(const short8*)(Ar + (V & 3) * 8192 + 2 * 512); \
        short8 a3_ = *(const short8*)(Ar + (V & 3) * 8192 + 3 * 512); \
        short8 a4_ = *(const short8*)(Ar + (V & 3) * 8192 + 4 * 512); \
        short8 a5_ = *(const short8*)(Ar + (V & 3) * 8192 + 5 * 512); \
        short8 a6_ = *(const short8*)(Ar + (V & 3) * 8192 + 6 * 512); \
        short8 a7_ = *(const short8*)(Ar + (V & 3) * 8192 + 7 * 512); \
        short8 b0_ = *(const short8*)(Br + (V & 3) * 8192 + 0 * 512); \
        short8 b1_ = *(const short8*)(Br + (V & 3) * 8192 + 1 * 512); \
        short8 b2_ = *(const short8*)(Br + (V & 3) * 8192 + 2 * 512); \
        short8 b3_ = *(const short8*)(Br + (V & 3) * 8192 + 3 * 512); \
        if ((V) < 14) { \
            GLDS0(aB0 + ((V) + 2) * 32,          Ad + (((V) + 2) & 3) * 8192); \
            GLDS0(aB1 + ((V) + 2) * 32,          Ad + (((V) + 2) & 3) * 8192 + 4096); \
            GLDS0(pB0c + (((V) + 2) & 15) * 32,  Bd + (((V) + 2) & 3) * 8192); \
            GLDS0(pB1c + (((V) + 2) & 15) * 32,  Bd + (((V) + 2) & 3) * 8192 + 4096); \
            asm volatile("s_waitcnt vmcnt(4)" ::: "memory"); \
        } else if (kk < 8) { \
            GLDS0(aB0 + ((V) + 2) * 32,          Ad + (((V) + 2) & 3) * 8192); \
            GLDS0(aB1 + ((V) + 2) * 32,          Ad + (((V) + 2) & 3) * 8192 + 4096); \
            GLDS0(pB0n + (((V) + 2) & 15) * 32,  Bd + (((V) + 2) & 3) * 8192); \
            GLDS0(pB1n + (((V) + 2) & 15) * 32,  Bd + (((V) + 2) & 3) * 8192 + 4096); \
            asm volatile("s_waitcnt vmcnt(4)" ::: "memory"); \
        } else { \
            asm volatile("s_waitcnt vmcnt(0)" ::: "memory"); \
        } \
        __builtin_amdgcn_s_barrier(); \
        __builtin_amdgcn_s_setprio(1); \
        MR(a0_, 0); MR(a1_, 1); MR(a2_, 2); MR(a3_, 3); \
        MR(a4_, 4); MR(a5_, 5); MR(a6_, 6); MR(a7_, 7); \
        __builtin_amdgcn_s_setprio(0); \
    } while (0)

    #pragma unroll 1
    for (int kk = 0; kk < 9; ++kk) {
        const int kn  = kk + 1;
        const int kdn = (kn * 11) >> 5;          // kn/3
        const int dhn = kdn - 1, dwn = kn - kdn * 3 - 1;
        const __hip_bfloat16* pB0n = MKB(dhn, dwn, 0);
        const __hip_bfloat16* pB1n = MKB(dhn, dwn, 1);

        WIN(0);  WIN(1);  WIN(2);  WIN(3);
        WIN(4);  WIN(5);  WIN(6);  WIN(7);
        WIN(8);  WIN(9);  WIN(10); WIN(11);
        WIN(12); WIN(13); WIN(14); WIN(15);

        pB0c = pB0n; pB1c = pB1n;
        aB0 += 512;  aB1 += 512;
    }
    #undef WIN
    #undef MR
    #undef MKB

    // epilogue: demod * acc + nw*noise, leaky-relu * sqrt(2)
    const float nwv = nw_p[0];
    const int colp = lane & 15;
    const int rgrp = (lane >> 4) * 4;
    float nz[4];
    #pragma unroll
    for (int ni = 0; ni < 4; ++ni)
        nz[ni] = noise[b * 4096 + p0 + wn * 64 + ni * 16 + colp] * nwv;
    #pragma unroll
    for (int mi = 0; mi < 8; ++mi) {
        const int obase = o0 + wm * 128 + mi * 16 + rgrp;
        float dm[4];
        #pragma unroll
        for (int j = 0; j < 4; ++j) dm[j] = demod[b * COUT_ + obase + j];
        #pragma unroll
        for (int ni = 0; ni < 4; ++ni) {
            const int pix = p0 + wn * 64 + ni * 16 + colp;
            #pragma unroll
            for (int j = 0; j < 4; ++j) {
                float v = acc[mi][ni][j] * dm[j] + nz[ni];
                v = (v >= 0.f ? v : 0.2f * v) * 1.4142135623730951f;
                out[(b * COUT_ + obase + j) * 4096 + pix] = v;
            }
        }
    }
}

extern "C" void kernel_launch(void* const* d_in, const int* in_sizes, int n_in,
                              void* d_out, int out_size, void* d_ws, size_t ws_size,
                              hipStream_t stream) {
    const float* x      = (const float*)d_in[0];
    const float* w      = (const float*)d_in[1];
    const float* noise  = (const float*)d_in[2];
    const float* lin_w  = (const float*)d_in[3];
    const float* lin_b  = (const float*)d_in[4];
    const float* conv_w = (const float*)d_in[5];
    const float* nw     = (const float*)d_in[6];
    float* out = (float*)d_out;

    char* ws = (char*)d_ws;
    __hip_bfloat16* xq = (__hip_bfloat16*)ws;                    // 67108864 B (NHWC bf16)
    __hip_bfloat16* w2 = (__hip_bfloat16*)(ws + 67108864);       //  4718592 B
    float* s     = (float*)(ws + 71827456);                      //    32768 B
    float* demod = (float*)(ws + 71860224);                      //    32768 B
    float* wsq   = (float*)(ws + 71892992);                      //  1048576 B
    float* zbuf  = (float*)(ws + 72941568);                      //     1024 B (zero page)

    static int lds_set = 0;
    if (!lds_set) {
        (void)hipFuncSetAttribute((const void*)conv_kernel,
                                  hipFuncAttributeMaxDynamicSharedMemorySize, 131072);
        lds_set = 1;
    }

    style_kernel<<<2048, 256, 0, stream>>>(w, lin_w, lin_b, s);
    prep_weights<<<512, 256, 0, stream>>>(conv_w, w2, wsq, zbuf);
    demod_kernel<<<2048, 256, 0, stream>>>(wsq, s, demod);
    upsample_mod_kernel<<<dim3(4, 16, 16), 256, 0, stream>>>(x, s, xq);
    conv_kernel<<<512, 512, 131072, stream>>>(xq, w2, demod, noise, nw, out,
                                              (const __hip_bfloat16*)zbuf);
}